// Round 9
// baseline (516.921 us; speedup 1.0000x reference)
//
#include <hip/hip_runtime.h>
#include <hip/hip_bf16.h>

// GCN 2-layer: h = relu(Anorm @ (x@W1) + b1); out = Anorm @ (h@W2) + b2
// R18 changes vs R17 (267.9us, best):
//  - ONE persistent mega-kernel with grid-wide generation barriers
//    (device-scope __hip_atomic ACQ/REL + __threadfence; grid sized by
//    hipOccupancyMaxActiveBlocksPerMultiprocessor x CUs -> co-residency
//    guaranteed, no deadlock). Chain 5 dispatches -> 2 (memset + mega).
//  - Phase B overlaps fine_csr with gemm1 (independent, previously
//    serialized across a dispatch boundary).
//  - Phase C (agg128+gemm2) stages W2 ONCE per block (amortized over
//    ~6 items vs once per 32-node block before).
//  - All phase bodies are the R17-proven forms, re-indexed for 512
//    threads + block-stride item loops.

#define BSH 8                 // bucket = dst >> 8 (256 nodes/bucket)
#define NBMAX 512
#define BCAP 5632             // fixed slots per bucket (mean 4096, +24 sigma)
#define MT 512                // mega-kernel threads

typedef unsigned int uint;
typedef unsigned short ushort;
typedef __attribute__((ext_vector_type(8))) short short8;
typedef __attribute__((ext_vector_type(4))) float floatx4;

__device__ __forceinline__ uint pack_bf16(float a, float b) {
    __hip_bfloat162 h = __float22bfloat162_rn(make_float2(a, b));
    return *reinterpret_cast<uint*>(&h);
}
__device__ __forceinline__ float bf16_lo(uint q) { return __uint_as_float(q << 16); }
__device__ __forceinline__ float bf16_hi(uint q) { return __uint_as_float(q & 0xffff0000u); }

// ---- grid-wide generation barrier (agent scope, co-resident grid) ----
__device__ __forceinline__ void grid_sync(int* cnt, int* gen, int nb) {
    __syncthreads();
    if (threadIdx.x == 0) {
        __threadfence();   // make this block's writes agent-visible
        int g = __hip_atomic_load(gen, __ATOMIC_RELAXED, __HIP_MEMORY_SCOPE_AGENT);
        int tk = __hip_atomic_fetch_add(cnt, 1, __ATOMIC_ACQ_REL, __HIP_MEMORY_SCOPE_AGENT);
        if (tk == nb - 1) {
            __hip_atomic_store(cnt, 0, __ATOMIC_RELAXED, __HIP_MEMORY_SCOPE_AGENT);
            __hip_atomic_store(gen, g + 1, __ATOMIC_RELEASE, __HIP_MEMORY_SCOPE_AGENT);
        } else {
            while (__hip_atomic_load(gen, __ATOMIC_ACQUIRE, __HIP_MEMORY_SCOPE_AGENT) == g)
                __builtin_amdgcn_s_sleep(8);
        }
        __threadfence();   // invalidate stale lines before consuming
    }
    __syncthreads();
}

__global__ __launch_bounds__(MT) void gcn_mega(
    const int* __restrict__ src, const int* __restrict__ dst,
    const float* __restrict__ X, const float* __restrict__ W1,
    const float* __restrict__ b1, const float* __restrict__ W2,
    const float* __restrict__ b2,
    int* __restrict__ bfill, int* __restrict__ bar,
    uint* __restrict__ staged, int4* __restrict__ meta,
    float* __restrict__ dinv, int* __restrict__ rec,
    uint* __restrict__ hq, uint* __restrict__ h2q,
    float* __restrict__ out,
    int e, int n, int nb, int pitems, int gitems, int citems, int ditems) {
    __shared__ __attribute__((aligned(16))) char smem[35840];
    int t = threadIdx.x;
    const int G = gridDim.x;
    int* bcnt = bar;
    int* bgen = bar + 1;

    // ================= PHASE A: edge partition (4096 edges/item) =========
    {
        uint* eP = (uint*)smem;                     // 4096 uint (16 KB)
        ushort* eB = (ushort*)(smem + 16384);       // 4096 ushort (8 KB)
        int* hist = (int*)(smem + 24576);           // 512 int (2 KB)
        int* base = (int*)(smem + 26624);           // 512 int (2 KB)
        for (int it = blockIdx.x; it < pitems; it += G) {
            __syncthreads();
            int e0 = it * 4096;
            for (int b = t; b < nb; b += MT) hist[b] = 0;
            __syncthreads();
#pragma unroll
            for (int v = 0; v < 2; v++) {
                int li = t * 8 + v * 4;
                int gi = e0 + li;
                int4 s4, d4;
                if (gi + 3 < e) {
                    s4 = *(const int4*)&src[gi];
                    d4 = *(const int4*)&dst[gi];
                } else {
                    const int* sp = &src[gi];
                    const int* dp = &dst[gi];
                    s4.x = (gi + 0 < e) ? sp[0] : 0;  d4.x = (gi + 0 < e) ? dp[0] : -1;
                    s4.y = (gi + 1 < e) ? sp[1] : 0;  d4.y = (gi + 1 < e) ? dp[1] : -1;
                    s4.z = (gi + 2 < e) ? sp[2] : 0;  d4.z = (gi + 2 < e) ? dp[2] : -1;
                    s4.w = (gi + 3 < e) ? sp[3] : 0;  d4.w = (gi + 3 < e) ? dp[3] : -1;
                }
                uint4 p4;
                p4.x = ((uint)s4.x << 8) | ((uint)d4.x & 255u);
                p4.y = ((uint)s4.y << 8) | ((uint)d4.y & 255u);
                p4.z = ((uint)s4.z << 8) | ((uint)d4.z & 255u);
                p4.w = ((uint)s4.w << 8) | ((uint)d4.w & 255u);
                *(uint4*)&eP[li] = p4;
                eB[li + 0] = (d4.x >= 0) ? (ushort)(d4.x >> BSH) : (ushort)0xFFFF;
                eB[li + 1] = (d4.y >= 0) ? (ushort)(d4.y >> BSH) : (ushort)0xFFFF;
                eB[li + 2] = (d4.z >= 0) ? (ushort)(d4.z >> BSH) : (ushort)0xFFFF;
                eB[li + 3] = (d4.w >= 0) ? (ushort)(d4.w >> BSH) : (ushort)0xFFFF;
                if (d4.x >= 0) atomicAdd(&hist[d4.x >> BSH], 1);
                if (d4.y >= 0) atomicAdd(&hist[d4.y >> BSH], 1);
                if (d4.z >= 0) atomicAdd(&hist[d4.z >> BSH], 1);
                if (d4.w >= 0) atomicAdd(&hist[d4.w >> BSH], 1);
            }
            __syncthreads();
            for (int b = t; b < nb; b += MT) {
                int v = hist[b];
                base[b] = v ? (b * BCAP + atomicAdd(&bfill[b], v)) : 0;
                hist[b] = 0;
            }
            __syncthreads();
#pragma unroll
            for (int i = 0; i < 8; i++) {
                int li = t + i * MT;
                ushort bb = eB[li];
                if (bb != (ushort)0xFFFF) {
                    int r = atomicAdd(&hist[bb], 1);
                    staged[base[bb] + r] = eP[li];
                }
            }
        }
    }
    grid_sync(bcnt, bgen, G);

    // ============ PHASE B: fine_csr (items < nb) + gemm1 pool =============
    {
        int btot = nb + gitems;
        for (int it = blockIdx.x; it < btot; it += G) {
            if (it < nb) {
                // ---- fine_csr item (bucket b = it) ----
                uint* eL = (uint*)smem;                 // 8192 uint (32 KB)
                int* lcnt = (int*)(smem + 32768);       // 256 int
                int* ts = (int*)(smem + 33792);         // 512 int (red/tsum)
                int b = it;
                __syncthreads();
                int part = 0;
                for (int j = t; j < b; j += MT) part += bfill[j];
                ts[t] = part;
                if (t < 256) lcnt[t] = 0;
                __syncthreads();
                for (int off = 256; off > 0; off >>= 1) {
                    if (t < off) ts[t] += ts[t + off];
                    __syncthreads();
                }
                int s0 = ts[0];
                int m = bfill[b];
                int sb = b * BCAP;
                __syncthreads();           // everyone has s0; ts free for tsum
                for (int i = t; i < m; i += MT) {
                    uint pk = staged[sb + i];
                    eL[i] = pk;
                    atomicAdd(&lcnt[pk & 255u], 1);
                }
                __syncthreads();
                int v = 0, x = 0;
                if (t < 256) { v = lcnt[t]; ts[t] = v; x = v; }
                __syncthreads();
                for (int off = 1; off < 256; off <<= 1) {
                    int y = 0;
                    if (t < 256 && t >= off) y = ts[t - off];
                    __syncthreads();
                    if (t < 256) { x += y; ts[t] = x; }
                    __syncthreads();
                }
                if (t < 256) {
                    int excl = x - v;
                    int node = (b << BSH) + t;
                    if (node < n) {
                        float di = rsqrtf((float)v + 1.0f);
                        dinv[node] = di;
                        meta[node] = make_int4(s0 + excl, v, __float_as_int(di),
                                               __float_as_int(di * di));
                    }
                    lcnt[t] = s0 + excl;   // absolute cursor
                }
                __syncthreads();
                for (int i = t; i < m; i += MT) {
                    uint pk = eL[i];
                    int pos = atomicAdd(&lcnt[pk & 255u], 1);
                    rec[pos] = (int)(pk >> 8);
                }
            } else {
                // ---- gemm1 item: 64 rows, hq = bf16(X @ W1), RAW ----
                ushort* sX = (ushort*)smem;             // 64*128 (16 KB)
                ushort* sWT = (ushort*)(smem + 16384);  // 64*128 (16 KB)
                int rbase = (it - nb) * 64;
                __syncthreads();
#pragma unroll
                for (int i = 0; i < 4; i++) {
                    int f = t + MT * i;
                    int r = f >> 5;
                    int c4 = f & 31;
                    float4 v = make_float4(0.f, 0.f, 0.f, 0.f);
                    int gr = rbase + r;
                    if (gr < n) v = *(const float4*)(X + (size_t)gr * 128 + c4 * 4);
                    uint lo = pack_bf16(v.x, v.y);
                    uint hi = pack_bf16(v.z, v.w);
                    int chunk = c4 >> 1;
                    int sub = (c4 & 1) * 4;
                    int off = r * 128 + (((chunk ^ (r & 15)) << 3) + sub);
                    *(uint2*)&sX[off] = make_uint2(lo, hi);
                }
                for (int ch = 0; ch < 2; ch++) {
                    __syncthreads();   // sX stores done (ch0) / prior mfma done (ch1)
#pragma unroll
                    for (int i = 0; i < 2; i++) {
                        int u = t + MT * i;        // (kp 0..63, n4 0..15)
                        int kp = u >> 4;
                        int n4 = u & 15;
                        int k = kp * 2;
                        const float* w0p = W1 + (size_t)k * 128 + ch * 64 + n4 * 4;
                        const float* w1p = W1 + (size_t)(k + 1) * 128 + ch * 64 + n4 * 4;
                        float4 w0 = *(const float4*)w0p;
                        float4 w1 = *(const float4*)w1p;
                        int chunk = k >> 3;
                        int sub = k & 7;
                        const float* a0 = (const float*)&w0;
                        const float* a1 = (const float*)&w1;
#pragma unroll
                        for (int j = 0; j < 4; j++) {
                            int nn = n4 * 4 + j;
                            uint pk = pack_bf16(a0[j], a1[j]);
                            *(uint*)&sWT[nn * 128 + (((chunk ^ (nn & 15)) << 3) + sub)] = pk;
                        }
                    }
                    __syncthreads();
                    int lane = t & 63;
                    int wave = t >> 6;
                    int m = lane & 15;
                    int q = lane >> 4;
                    int rt = wave >> 1;            // 0..3 row tile
                    int ctl = wave & 1;            // 0..1 col 32-chunk
                    floatx4 acc[2];
                    acc[0] = (floatx4){0.f, 0.f, 0.f, 0.f};
                    acc[1] = (floatx4){0.f, 0.f, 0.f, 0.f};
#pragma unroll
                    for (int ks = 0; ks < 4; ks++) {
                        int rr = rt * 16 + m;
                        int ca = (ks * 4 + q) ^ (rr & 15);
                        short8 afrag = *(const short8*)&sX[rr * 128 + (ca << 3)];
#pragma unroll
                        for (int c = 0; c < 2; c++) {
                            int nn = ctl * 32 + c * 16 + m;
                            int cb = (ks * 4 + q) ^ (nn & 15);
                            short8 bfrag = *(const short8*)&sWT[nn * 128 + (cb << 3)];
                            acc[c] = __builtin_amdgcn_mfma_f32_16x16x32_bf16(bfrag, afrag, acc[c], 0, 0, 0);
                        }
                    }
                    int gr = rbase + rt * 16 + m;
                    if (gr < n) {
#pragma unroll
                        for (int c = 0; c < 2; c++) {
                            int T = ch * 4 + ctl * 2 + c;   // 16-col tile index
                            uint2 pk;
                            pk.x = pack_bf16(acc[c][0], acc[c][1]);
                            pk.y = pack_bf16(acc[c][2], acc[c][3]);
                            *(uint2*)&hq[(size_t)gr * 64 + T * 8 + q * 2] = pk;
                        }
                    }
                }
            }
        }
    }
    grid_sync(bcnt, bgen, G);

    // ========= PHASE C: agg128 (per-edge weights) + GEMM2 fused ===========
    {
        ushort* sWT = (ushort*)smem;               // 64*128 (16 KB), W2^T
        ushort* sg = (ushort*)(smem + 16384);      // 32*128 (8 KB)
        const uint4* h4 = (const uint4*)hq;
        // stage W2^T once per block
        __syncthreads();
#pragma unroll
        for (int i = 0; i < 2; i++) {
            int u = t + MT * i;
            int kp = u >> 4;
            int n4 = u & 15;
            int k = kp * 2;
            float4 w0 = *(const float4*)(W2 + (size_t)k * 64 + n4 * 4);
            float4 w1 = *(const float4*)(W2 + (size_t)(k + 1) * 64 + n4 * 4);
            int chunk = k >> 3;
            int sub = k & 7;
            const float* a0f = (const float*)&w0;
            const float* a1f = (const float*)&w1;
#pragma unroll
            for (int j = 0; j < 4; j++) {
                int nn = n4 * 4 + j;
                uint pk = pack_bf16(a0f[j], a1f[j]);
                *(uint*)&sWT[nn * 128 + (((chunk ^ (nn & 15)) << 3) + sub)] = pk;
            }
        }

        int qw = t >> 4;
        int fl = t & 15;
        for (int it = blockIdx.x; it < citems; it += G) {
            int nb0 = it * 32;
            int w = nb0 + qw;
            bool valid = w < n;
            int wsafe = valid ? w : 0;
            int4 mt = meta[wsafe];
            int j0 = mt.x;
            int deg = valid ? mt.y : 0;
            float di = __int_as_float(mt.z);
            float swq = valid ? __int_as_float(mt.w) : 0.f;

            uint4 qs = h4[(size_t)wsafe * 16 + fl];
            float a0 = bf16_lo(qs.x) * swq, a1 = bf16_hi(qs.x) * swq;
            float a2 = bf16_lo(qs.y) * swq, a3 = bf16_hi(qs.y) * swq;
            float a4 = bf16_lo(qs.z) * swq, a5 = bf16_hi(qs.z) * swq;
            float a6 = bf16_lo(qs.w) * swq, a7 = bf16_hi(qs.w) * swq;

            const int* rp = rec + j0;
            int tt = 0;
            for (; tt + 8 <= deg; tt += 8) {
                int s[8]; float wf[8]; uint4 q[8];
#pragma unroll
                for (int u = 0; u < 8; u++) s[u] = rp[tt + u];
#pragma unroll
                for (int u = 0; u < 8; u++) wf[u] = dinv[s[u]] * di;
#pragma unroll
                for (int u = 0; u < 8; u++) q[u] = h4[(size_t)s[u] * 16 + fl];
#pragma unroll
                for (int u = 0; u < 8; u++) {
                    a0 += bf16_lo(q[u].x) * wf[u]; a1 += bf16_hi(q[u].x) * wf[u];
                    a2 += bf16_lo(q[u].y) * wf[u]; a3 += bf16_hi(q[u].y) * wf[u];
                    a4 += bf16_lo(q[u].z) * wf[u]; a5 += bf16_hi(q[u].z) * wf[u];
                    a6 += bf16_lo(q[u].w) * wf[u]; a7 += bf16_hi(q[u].w) * wf[u];
                }
            }
            for (; tt + 2 <= deg; tt += 2) {
                int s0i = rp[tt], s1i = rp[tt + 1];
                float w0v = dinv[s0i] * di, w1v = dinv[s1i] * di;
                uint4 q0 = h4[(size_t)s0i * 16 + fl];
                uint4 q1 = h4[(size_t)s1i * 16 + fl];
                a0 += bf16_lo(q0.x) * w0v + bf16_lo(q1.x) * w1v;
                a1 += bf16_hi(q0.x) * w0v + bf16_hi(q1.x) * w1v;
                a2 += bf16_lo(q0.y) * w0v + bf16_lo(q1.y) * w1v;
                a3 += bf16_hi(q0.y) * w0v + bf16_hi(q1.y) * w1v;
                a4 += bf16_lo(q0.z) * w0v + bf16_lo(q1.z) * w1v;
                a5 += bf16_hi(q0.z) * w0v + bf16_hi(q1.z) * w1v;
                a6 += bf16_lo(q0.w) * w0v + bf16_lo(q1.w) * w1v;
                a7 += bf16_hi(q0.w) * w0v + bf16_hi(q1.w) * w1v;
            }
            if (tt < deg) {
                int s = rp[tt];
                float wv = dinv[s] * di;
                uint4 q0 = h4[(size_t)s * 16 + fl];
                a0 += bf16_lo(q0.x) * wv; a1 += bf16_hi(q0.x) * wv;
                a2 += bf16_lo(q0.y) * wv; a3 += bf16_hi(q0.y) * wv;
                a4 += bf16_lo(q0.z) * wv; a5 += bf16_hi(q0.z) * wv;
                a6 += bf16_lo(q0.w) * wv; a7 += bf16_hi(q0.w) * wv;
            }

            float4 bb0 = *(const float4*)&b1[8 * fl];
            float4 bb1 = *(const float4*)&b1[8 * fl + 4];
            uint4 pkv;
            pkv.x = pack_bf16(fmaxf(a0 + bb0.x, 0.f), fmaxf(a1 + bb0.y, 0.f));
            pkv.y = pack_bf16(fmaxf(a2 + bb0.z, 0.f), fmaxf(a3 + bb0.w, 0.f));
            pkv.z = pack_bf16(fmaxf(a4 + bb1.x, 0.f), fmaxf(a5 + bb1.y, 0.f));
            pkv.w = pack_bf16(fmaxf(a6 + bb1.z, 0.f), fmaxf(a7 + bb1.w, 0.f));
            __syncthreads();            // previous item's MFMA finished with sg
            *(uint4*)&sg[qw * 128 + ((fl ^ (qw & 15)) << 3)] = pkv;
            __syncthreads();

            int wave = t >> 6;
            int lane = t & 63;
            int m = lane & 15;
            int qq = lane >> 4;
            int rt = wave >> 2;
            int ct = wave & 3;
            floatx4 acc = (floatx4){0.f, 0.f, 0.f, 0.f};
#pragma unroll
            for (int ks = 0; ks < 4; ks++) {
                int rr = rt * 16 + m;
                int ca = (ks * 4 + qq) ^ (rr & 15);
                short8 afrag = *(const short8*)&sg[rr * 128 + (ca << 3)];
                int nn = ct * 16 + m;
                int cb = (ks * 4 + qq) ^ (nn & 15);
                short8 bfrag = *(const short8*)&sWT[nn * 128 + (cb << 3)];
                acc = __builtin_amdgcn_mfma_f32_16x16x32_bf16(bfrag, afrag, acc, 0, 0, 0);
            }
            int gr = nb0 + rt * 16 + m;
            if (gr < n) {
                float sc = dinv[gr];
                uint2 pk;
                pk.x = pack_bf16(acc[0] * sc, acc[1] * sc);
                pk.y = pack_bf16(acc[2] * sc, acc[3] * sc);
                *(uint2*)&h2q[(size_t)gr * 32 + ct * 8 + qq * 2] = pk;
            }
        }
    }
    grid_sync(bcnt, bgen, G);

    // ============ PHASE D: layer-2 aggregation (pre-scaled h2q) ===========
    {
        const uint4* h4 = (const uint4*)h2q;
        int fl = t & 7;
        for (int it = blockIdx.x; it < ditems; it += G) {
            int w = it * 64 + (t >> 3);
            if (w >= n) continue;
            int4 mt = meta[w];
            int j0 = mt.x;
            int deg = mt.y;
            float di = __int_as_float(mt.z);

            uint4 qs = h4[(size_t)w * 8 + fl];
            float a0 = bf16_lo(qs.x), a1 = bf16_hi(qs.x);
            float a2 = bf16_lo(qs.y), a3 = bf16_hi(qs.y);
            float a4 = bf16_lo(qs.z), a5 = bf16_hi(qs.z);
            float a6 = bf16_lo(qs.w), a7 = bf16_hi(qs.w);

            const int* rp = rec + j0;
            int tt = 0;
            for (; tt + 8 <= deg; tt += 8) {
                int s[8]; uint4 q[8];
#pragma unroll
                for (int u = 0; u < 8; u++) s[u] = rp[tt + u];
#pragma unroll
                for (int u = 0; u < 8; u++) q[u] = h4[(size_t)s[u] * 8 + fl];
#pragma unroll
                for (int u = 0; u < 8; u++) {
                    a0 += bf16_lo(q[u].x); a1 += bf16_hi(q[u].x);
                    a2 += bf16_lo(q[u].y); a3 += bf16_hi(q[u].y);
                    a4 += bf16_lo(q[u].z); a5 += bf16_hi(q[u].z);
                    a6 += bf16_lo(q[u].w); a7 += bf16_hi(q[u].w);
                }
            }
            for (; tt + 2 <= deg; tt += 2) {
                int s0i = rp[tt], s1i = rp[tt + 1];
                uint4 q0 = h4[(size_t)s0i * 8 + fl];
                uint4 q1 = h4[(size_t)s1i * 8 + fl];
                a0 += bf16_lo(q0.x) + bf16_lo(q1.x);
                a1 += bf16_hi(q0.x) + bf16_hi(q1.x);
                a2 += bf16_lo(q0.y) + bf16_lo(q1.y);
                a3 += bf16_hi(q0.y) + bf16_hi(q1.y);
                a4 += bf16_lo(q0.z) + bf16_lo(q1.z);
                a5 += bf16_hi(q0.z) + bf16_hi(q1.z);
                a6 += bf16_lo(q0.w) + bf16_lo(q1.w);
                a7 += bf16_hi(q0.w) + bf16_hi(q1.w);
            }
            if (tt < deg) {
                int s = rp[tt];
                uint4 q0 = h4[(size_t)s * 8 + fl];
                a0 += bf16_lo(q0.x); a1 += bf16_hi(q0.x);
                a2 += bf16_lo(q0.y); a3 += bf16_hi(q0.y);
                a4 += bf16_lo(q0.z); a5 += bf16_hi(q0.z);
                a6 += bf16_lo(q0.w); a7 += bf16_hi(q0.w);
            }

            float4 bb0 = *(const float4*)&b2[8 * fl];
            float4 bb1 = *(const float4*)&b2[8 * fl + 4];
            float4 o0, o1;
            o0.x = di * a0 + bb0.x; o0.y = di * a1 + bb0.y;
            o0.z = di * a2 + bb0.z; o0.w = di * a3 + bb0.w;
            o1.x = di * a4 + bb1.x; o1.y = di * a5 + bb1.y;
            o1.z = di * a6 + bb1.z; o1.w = di * a7 + bb1.w;
            *(float4*)&out[(size_t)w * 64 + 8 * fl] = o0;
            *(float4*)&out[(size_t)w * 64 + 8 * fl + 4] = o1;
        }
    }
}

extern "C" void kernel_launch(void* const* d_in, const int* in_sizes, int n_in,
                              void* d_out, int out_size, void* d_ws, size_t ws_size,
                              hipStream_t stream) {
    const float* x = (const float*)d_in[0];
    const int* edge = (const int*)d_in[1];
    const float* W1 = (const float*)d_in[2];
    const float* b1 = (const float*)d_in[3];
    const float* W2 = (const float*)d_in[4];
    const float* b2 = (const float*)d_in[5];

    const int N = in_sizes[0] / 128;
    const int E = in_sizes[1] / 2;
    const int* src = edge;
    const int* dst = edge + E;
    const int NB = (N + (1 << BSH) - 1) >> BSH;

    // workspace carve-up
    char* p = (char*)d_ws;
    int* bfill = (int*)p;     p += NBMAX * 4;
    int* bar = (int*)p;       p += 64;                  // barrier cnt/gen (own line)
    float* dinv = (float*)p;  p += (size_t)N * 4;
    int4* meta = (int4*)p;    p += (size_t)N * 16;
    int* rec = (int*)p;       p += (size_t)E * 4;
    uint* staged = (uint*)p;  p += (size_t)NBMAX * BCAP * 4;
    uint* hq = (uint*)p;      p += (size_t)N * 64 * 4;  // RAW x@W1 bf16
    uint* h2q = (uint*)p;     p += (size_t)N * 32 * 4;  // dinv[r]*h2 bf16

    float* out = (float*)d_out;
    const int pitems = (E + 4095) / 4096;
    const int gitems = (N + 63) / 64;
    const int citems = (N + 31) / 32;
    const int ditems = (N + 63) / 64;

    // co-resident grid size (computed once; occupancy-API-derived)
    static int g_blocks = 0;
    if (g_blocks == 0) {
        int occ = 0;
        if (hipOccupancyMaxActiveBlocksPerMultiprocessor(
                &occ, (const void*)gcn_mega, MT, 0) != hipSuccess || occ < 1)
            occ = 1;
        int dev = 0;
        (void)hipGetDevice(&dev);
        int cus = 0;
        if (hipDeviceGetAttribute(&cus, hipDeviceAttributeMultiprocessorCount,
                                  dev) != hipSuccess || cus < 1)
            cus = 256;
        g_blocks = occ * cus;
        if (g_blocks > 2048) g_blocks = 2048;
    }

    (void)hipMemsetAsync(bfill, 0, NBMAX * 4 + 64, stream);
    gcn_mega<<<g_blocks, MT, 0, stream>>>(
        src, dst, x, W1, b1, W2, b2,
        bfill, bar, staged, meta, dinv, rec, hq, h2q, out,
        E, N, NB, pitems, gitems, citems, ditems);
}

// Round 11
// 267.366 us; speedup vs baseline: 1.9334x; 1.9334x over previous
//
#include <hip/hip_runtime.h>
#include <hip/hip_bf16.h>

// GCN 2-layer: h = relu(Anorm @ (x@W1) + b1); out = Anorm @ (h@W2) + b2
// R20 = R19 with the compile fix: __builtin_nontemporal_store needs a
// clang ext_vector_type, not HIP's struct float4. Stores go through
// floatx4 (ext_vector_type(4) float).
//  - R17 structure (267.9us best): memset, part_gemm1 (merged), fine_csr,
//    agg128_mm64 (fused gemm2), aggregate64q. Each phase at its measured
//    floor (agg128: 186MB compulsory misses / 2.9TB/s fabric ceiling).
//  - aggregate64q writes `out` non-temporally (25.6MB streaming, never
//    re-read) -> preserves h2q (12.8MB) in L2.

#define NTHREADS 256
#define BSH 8                 // bucket = dst >> 8 (256 nodes/bucket)
#define NBMAX 512
#define BCAP 5632             // fixed slots per bucket (mean 4096, +24 sigma)
#define FC_CAP 8192           // LDS edge cache per bucket

typedef unsigned int uint;
typedef unsigned short ushort;
typedef __attribute__((ext_vector_type(8))) short short8;
typedef __attribute__((ext_vector_type(4))) float floatx4;

__device__ __forceinline__ uint pack_bf16(float a, float b) {
    __hip_bfloat162 h = __float22bfloat162_rn(make_float2(a, b));
    return *reinterpret_cast<uint*>(&h);
}
__device__ __forceinline__ float bf16_lo(uint q) { return __uint_as_float(q << 16); }
__device__ __forceinline__ float bf16_hi(uint q) { return __uint_as_float(q & 0xffff0000u); }

// ---------- MERGED: edge partition (blocks < eblocks) + GEMM1 (rest) ----------
__global__ __launch_bounds__(256) void part_gemm1(
    const int* __restrict__ src, const int* __restrict__ dst,
    int* __restrict__ bfill, uint* __restrict__ staged, int e, int nb, int eblocks,
    const float* __restrict__ X, const float* __restrict__ W1,
    uint* __restrict__ hq, int n) {
    __shared__ __align__(16) char smem[49152];
    int t = threadIdx.x;

    if ((int)blockIdx.x < eblocks) {
        // ---------------- partition branch (16 KB of smem) ----------------
        uint* eP = (uint*)smem;                    // 2048 uint  (8 KB)
        ushort* eB = (ushort*)(smem + 8192);       // 2048 ushort(4 KB)
        int* hist = (int*)(smem + 12288);          // 512 int   (2 KB)
        int* base = (int*)(smem + 14336);          // 512 int   (2 KB)
        int e0 = blockIdx.x * 2048;

        for (int b = t; b < nb; b += 256) hist[b] = 0;
        __syncthreads();
#pragma unroll
        for (int v = 0; v < 2; v++) {
            int li = t * 8 + v * 4;
            int gi = e0 + li;
            int4 s4, d4;
            if (gi + 3 < e) {
                s4 = *(const int4*)&src[gi];
                d4 = *(const int4*)&dst[gi];
            } else {
                const int* sp = &src[gi];
                const int* dp = &dst[gi];
                s4.x = (gi + 0 < e) ? sp[0] : 0;  d4.x = (gi + 0 < e) ? dp[0] : -1;
                s4.y = (gi + 1 < e) ? sp[1] : 0;  d4.y = (gi + 1 < e) ? dp[1] : -1;
                s4.z = (gi + 2 < e) ? sp[2] : 0;  d4.z = (gi + 2 < e) ? dp[2] : -1;
                s4.w = (gi + 3 < e) ? sp[3] : 0;  d4.w = (gi + 3 < e) ? dp[3] : -1;
            }
            uint4 p4;
            p4.x = ((uint)s4.x << 8) | ((uint)d4.x & 255u);
            p4.y = ((uint)s4.y << 8) | ((uint)d4.y & 255u);
            p4.z = ((uint)s4.z << 8) | ((uint)d4.z & 255u);
            p4.w = ((uint)s4.w << 8) | ((uint)d4.w & 255u);
            *(uint4*)&eP[li] = p4;
            eB[li + 0] = (d4.x >= 0) ? (ushort)(d4.x >> BSH) : (ushort)0xFFFF;
            eB[li + 1] = (d4.y >= 0) ? (ushort)(d4.y >> BSH) : (ushort)0xFFFF;
            eB[li + 2] = (d4.z >= 0) ? (ushort)(d4.z >> BSH) : (ushort)0xFFFF;
            eB[li + 3] = (d4.w >= 0) ? (ushort)(d4.w >> BSH) : (ushort)0xFFFF;
            if (d4.x >= 0) atomicAdd(&hist[d4.x >> BSH], 1);
            if (d4.y >= 0) atomicAdd(&hist[d4.y >> BSH], 1);
            if (d4.z >= 0) atomicAdd(&hist[d4.z >> BSH], 1);
            if (d4.w >= 0) atomicAdd(&hist[d4.w >> BSH], 1);
        }
        __syncthreads();
        for (int b = t; b < nb; b += 256) {
            int v = hist[b];
            base[b] = v ? (b * BCAP + atomicAdd(&bfill[b], v)) : 0;
            hist[b] = 0;   // reset for rank pass
        }
        __syncthreads();
#pragma unroll
        for (int i = 0; i < 8; i++) {
            int li = t + i * 256;
            ushort bb = eB[li];
            if (bb != (ushort)0xFFFF) {
                int r = atomicAdd(&hist[bb], 1);
                staged[base[bb] + r] = eP[li];
            }
        }
    } else {
        // ---------------- GEMM1 branch (48 KB of smem) ----------------
        ushort* sX = (ushort*)smem;                // 64*128 (16 KB)
        ushort* sWT = (ushort*)(smem + 16384);     // 128*128 (32 KB)
        int rbase = ((int)blockIdx.x - eblocks) * 64;

#pragma unroll
        for (int i = 0; i < 8; i++) {
            int f = t + 256 * i;
            int r = f >> 5;
            int c4 = f & 31;
            float4 v = make_float4(0.f, 0.f, 0.f, 0.f);
            int gr = rbase + r;
            if (gr < n) v = *(const float4*)(X + (size_t)gr * 128 + c4 * 4);
            uint lo = pack_bf16(v.x, v.y);
            uint hi = pack_bf16(v.z, v.w);
            int chunk = c4 >> 1;
            int sub = (c4 & 1) * 4;
            int off = r * 128 + (((chunk ^ (r & 15)) << 3) + sub);
            *(uint2*)&sX[off] = make_uint2(lo, hi);
        }
#pragma unroll
        for (int i = 0; i < 8; i++) {
            int u = t + 256 * i;           // (kp, n4), kp=u/32, n4=u%32
            int kp = u >> 5;
            int n4 = u & 31;
            int k = kp * 2;
            float4 w0 = *(const float4*)(W1 + (size_t)k * 128 + n4 * 4);
            float4 w1 = *(const float4*)(W1 + (size_t)(k + 1) * 128 + n4 * 4);
            int chunk = k >> 3;
            int sub = k & 7;
            const float* a0 = (const float*)&w0;
            const float* a1 = (const float*)&w1;
#pragma unroll
            for (int j = 0; j < 4; j++) {
                int nn = n4 * 4 + j;
                uint pk = pack_bf16(a0[j], a1[j]);
                int off = nn * 128 + (((chunk ^ (nn & 15)) << 3) + sub);
                *(uint*)&sWT[off] = pk;
            }
        }
        __syncthreads();

        int lane = t & 63;
        int wave = t >> 6;
        int m = lane & 15;
        int q = lane >> 4;
        int r0 = wave * 16;

        floatx4 acc[8];
#pragma unroll
        for (int c = 0; c < 8; c++) acc[c] = (floatx4){0.f, 0.f, 0.f, 0.f};

#pragma unroll
        for (int ks = 0; ks < 4; ks++) {
            int rr = r0 + m;
            int ca = (ks * 4 + q) ^ (rr & 15);
            short8 afrag = *(const short8*)&sX[rr * 128 + (ca << 3)];
#pragma unroll
            for (int c = 0; c < 8; c++) {
                int nn = c * 16 + m;
                int cb = (ks * 4 + q) ^ (nn & 15);
                short8 bfrag = *(const short8*)&sWT[nn * 128 + (cb << 3)];
                acc[c] = __builtin_amdgcn_mfma_f32_16x16x32_bf16(bfrag, afrag, acc[c], 0, 0, 0);
            }
        }

        int gr = rbase + r0 + m;
        if (gr < n) {
#pragma unroll
            for (int c = 0; c < 8; c++) {
                uint2 pk;
                pk.x = pack_bf16(acc[c][0], acc[c][1]);
                pk.y = pack_bf16(acc[c][2], acc[c][3]);
                *(uint2*)&hq[(size_t)gr * 64 + c * 8 + q * 2] = pk;
            }
        }
    }
}

// ---------- per-bucket fused CSR: dense offset by bfill reduction,
//            count+scan -> meta/dinv, LDS-cached fill ----------
__global__ __launch_bounds__(256) void fine_csr_kernel(
    const uint* __restrict__ staged, const int* __restrict__ bfill,
    int4* __restrict__ meta, float* __restrict__ dinv,
    int* __restrict__ rec, int n) {
    __shared__ uint eL[FC_CAP];      // 32 KB edge cache
    __shared__ int lcnt[256];
    __shared__ int tsum[256];
    __shared__ int red[256];
    int b = blockIdx.x;
    int t = threadIdx.x;

    // s0 = dense start = sum_{j<b} bfill[j]  (all blocks compute their own)
    int part = 0;
    for (int j = t; j < b; j += 256) part += bfill[j];
    red[t] = part;
    lcnt[t] = 0;
    __syncthreads();
    for (int off = 128; off > 0; off >>= 1) {
        if (t < off) red[t] += red[t + off];
        __syncthreads();
    }
    int s0 = red[0];
    int m = bfill[b];

    int sb = b * BCAP;               // sparse (staged) base for this bucket
    for (int i = t; i < m; i += 256) {
        uint pk = staged[sb + i];
        eL[i] = pk;                  // m <= BCAP < FC_CAP always
        atomicAdd(&lcnt[pk & 255u], 1);
    }
    __syncthreads();
    int v = lcnt[t];
    tsum[t] = v;
    __syncthreads();
    int x = v;
    for (int off = 1; off < 256; off <<= 1) {
        int y = (t >= off) ? tsum[t - off] : 0;
        __syncthreads();
        x += y;
        tsum[t] = x;
        __syncthreads();
    }
    int excl = x - v;
    int node = (b << BSH) + t;
    if (node < n) {
        float di = rsqrtf((float)v + 1.0f);
        dinv[node] = di;
        meta[node] = make_int4(s0 + excl, v, __float_as_int(di), __float_as_int(di * di));
    }
    lcnt[t] = s0 + excl;             // repurpose as absolute cursor
    __syncthreads();
    // fill: rec[pos] = src (edges come from LDS cache)
    for (int i = t; i < m; i += 256) {
        uint pk = eL[i];
        int pos = atomicAdd(&lcnt[pk & 255u], 1);
        rec[pos] = (int)(pk >> 8);
    }
}

// ---------- FUSED: aggregate layer-1 (D=128, per-edge weights) + GEMM2 ----------
__global__ __launch_bounds__(512) void agg128_mm64(
    const uint* __restrict__ hq, const int* __restrict__ rec,
    const int4* __restrict__ meta, const float* __restrict__ dinv,
    const float* __restrict__ bias, const float* __restrict__ W2,
    uint* __restrict__ h2q, int n) {
    __shared__ ushort sWT[64 * 128];   // 16 KB
    __shared__ ushort sg[32 * 128];    // 8 KB
    int t = threadIdx.x;

    // stage W2^T (f32 -> bf16, XOR swizzle)
#pragma unroll
    for (int i = 0; i < 2; i++) {
        int u = t + 512 * i;          // 0..1023 = (kp, n4)
        int kp = u >> 4;
        int n4 = u & 15;
        int k = kp * 2;
        float4 w0 = *(const float4*)(W2 + (size_t)k * 64 + n4 * 4);
        float4 w1 = *(const float4*)(W2 + (size_t)(k + 1) * 64 + n4 * 4);
        int chunk = k >> 3;
        int sub = k & 7;
        const float* a0f = (const float*)&w0;
        const float* a1f = (const float*)&w1;
#pragma unroll
        for (int j = 0; j < 4; j++) {
            int nn = n4 * 4 + j;
            uint pk = pack_bf16(a0f[j], a1f[j]);
            *(uint*)&sWT[nn * 128 + (((chunk ^ (nn & 15)) << 3) + sub)] = pk;
        }
    }

    int qw = t >> 4;                  // 0..31 local node
    int fl = t & 15;                  // uint4 lane: features 8*fl .. 8*fl+7
    int nb0 = blockIdx.x * 32;
    int w = nb0 + qw;
    bool valid = w < n;
    int wsafe = valid ? w : 0;
    const uint4* h4 = (const uint4*)hq;   // row = 16 uint4

    int4 mt = meta[wsafe];
    int j0 = mt.x;
    int deg = valid ? mt.y : 0;
    float di = __int_as_float(mt.z);
    float swq = valid ? __int_as_float(mt.w) : 0.f;   // di^2

    // self term (raw row, weight di^2)
    uint4 qs = h4[(size_t)wsafe * 16 + fl];
    float a0 = bf16_lo(qs.x) * swq, a1 = bf16_hi(qs.x) * swq;
    float a2 = bf16_lo(qs.y) * swq, a3 = bf16_hi(qs.y) * swq;
    float a4 = bf16_lo(qs.z) * swq, a5 = bf16_hi(qs.z) * swq;
    float a6 = bf16_lo(qs.w) * swq, a7 = bf16_hi(qs.w) * swq;

    const int* rp = rec + j0;
    int tt = 0;
    for (; tt + 8 <= deg; tt += 8) {
        int s[8]; float wf[8]; uint4 q[8];
#pragma unroll
        for (int u = 0; u < 8; u++) s[u] = rp[tt + u];
#pragma unroll
        for (int u = 0; u < 8; u++) wf[u] = dinv[s[u]] * di;
#pragma unroll
        for (int u = 0; u < 8; u++) q[u] = h4[(size_t)s[u] * 16 + fl];
#pragma unroll
        for (int u = 0; u < 8; u++) {
            a0 += bf16_lo(q[u].x) * wf[u]; a1 += bf16_hi(q[u].x) * wf[u];
            a2 += bf16_lo(q[u].y) * wf[u]; a3 += bf16_hi(q[u].y) * wf[u];
            a4 += bf16_lo(q[u].z) * wf[u]; a5 += bf16_hi(q[u].z) * wf[u];
            a6 += bf16_lo(q[u].w) * wf[u]; a7 += bf16_hi(q[u].w) * wf[u];
        }
    }
    for (; tt + 2 <= deg; tt += 2) {
        int s0i = rp[tt], s1i = rp[tt + 1];
        float w0v = dinv[s0i] * di, w1v = dinv[s1i] * di;
        uint4 q0 = h4[(size_t)s0i * 16 + fl];
        uint4 q1 = h4[(size_t)s1i * 16 + fl];
        a0 += bf16_lo(q0.x) * w0v + bf16_lo(q1.x) * w1v;
        a1 += bf16_hi(q0.x) * w0v + bf16_hi(q1.x) * w1v;
        a2 += bf16_lo(q0.y) * w0v + bf16_lo(q1.y) * w1v;
        a3 += bf16_hi(q0.y) * w0v + bf16_hi(q1.y) * w1v;
        a4 += bf16_lo(q0.z) * w0v + bf16_lo(q1.z) * w1v;
        a5 += bf16_hi(q0.z) * w0v + bf16_hi(q1.z) * w1v;
        a6 += bf16_lo(q0.w) * w0v + bf16_lo(q1.w) * w1v;
        a7 += bf16_hi(q0.w) * w0v + bf16_hi(q1.w) * w1v;
    }
    if (tt < deg) {
        int s = rp[tt];
        float wv = dinv[s] * di;
        uint4 q0 = h4[(size_t)s * 16 + fl];
        a0 += bf16_lo(q0.x) * wv; a1 += bf16_hi(q0.x) * wv;
        a2 += bf16_lo(q0.y) * wv; a3 += bf16_hi(q0.y) * wv;
        a4 += bf16_lo(q0.z) * wv; a5 += bf16_hi(q0.z) * wv;
        a6 += bf16_lo(q0.w) * wv; a7 += bf16_hi(q0.w) * wv;
    }

    // g = relu(acc + b1) -> bf16 -> LDS (weights fully applied per edge)
    float4 bb0 = *(const float4*)&bias[8 * fl];
    float4 bb1 = *(const float4*)&bias[8 * fl + 4];
    uint4 pkv;
    pkv.x = pack_bf16(fmaxf(a0 + bb0.x, 0.f), fmaxf(a1 + bb0.y, 0.f));
    pkv.y = pack_bf16(fmaxf(a2 + bb0.z, 0.f), fmaxf(a3 + bb0.w, 0.f));
    pkv.z = pack_bf16(fmaxf(a4 + bb1.x, 0.f), fmaxf(a5 + bb1.y, 0.f));
    pkv.w = pack_bf16(fmaxf(a6 + bb1.z, 0.f), fmaxf(a7 + bb1.w, 0.f));
    *(uint4*)&sg[qw * 128 + ((fl ^ (qw & 15)) << 3)] = pkv;
    __syncthreads();

    // h2 = g @ W2 : 32 rows x 64 cols, 8 waves = 2 row-tiles x 4 col-tiles
    int wave = t >> 6;
    int lane = t & 63;
    int m = lane & 15;
    int qq = lane >> 4;
    int rt = wave >> 2;               // row tile 0..1
    int ct = wave & 3;                // col tile 0..3
    floatx4 acc = (floatx4){0.f, 0.f, 0.f, 0.f};
#pragma unroll
    for (int ks = 0; ks < 4; ks++) {
        int rr = rt * 16 + m;
        int ca = (ks * 4 + qq) ^ (rr & 15);
        short8 afrag = *(const short8*)&sg[rr * 128 + (ca << 3)];
        int nn = ct * 16 + m;
        int cb = (ks * 4 + qq) ^ (nn & 15);
        short8 bfrag = *(const short8*)&sWT[nn * 128 + (cb << 3)];
        acc = __builtin_amdgcn_mfma_f32_16x16x32_bf16(bfrag, afrag, acc, 0, 0, 0);
    }
    int gr = nb0 + rt * 16 + m;
    if (gr < n) {
        float sc = dinv[gr];          // pre-scale h2 rows for layer-2 gather
        uint2 pk;
        pk.x = pack_bf16(acc[0] * sc, acc[1] * sc);
        pk.y = pack_bf16(acc[2] * sc, acc[3] * sc);
        *(uint2*)&h2q[(size_t)gr * 32 + ct * 8 + qq * 2] = pk;
    }
}

// ---------- pull aggregation, D=64 (pre-scaled bf16 in, f32 out) ----------
// eighth-wave: 8 lanes x uint4 = 128B row. `out` stores are NON-TEMPORAL
// (streaming, never re-read) to keep h2q resident in L2.
__global__ __launch_bounds__(256) void aggregate64q(
    const uint* __restrict__ hq, const int* __restrict__ rec,
    const int4* __restrict__ meta, const float* __restrict__ bias,
    float* __restrict__ out, int n) {
    int gt = blockIdx.x * 256 + threadIdx.x;
    int w = gt >> 3;
    if (w >= n) return;
    int fl = gt & 7;                  // features 8*fl .. 8*fl+7

    int4 mt = meta[w];
    int j0 = mt.x;
    int deg = mt.y;
    float di = __int_as_float(mt.z);
    const uint4* h4 = (const uint4*)hq;   // row = 8 uint4

    uint4 qs = h4[(size_t)w * 8 + fl];
    float a0 = bf16_lo(qs.x), a1 = bf16_hi(qs.x);
    float a2 = bf16_lo(qs.y), a3 = bf16_hi(qs.y);
    float a4 = bf16_lo(qs.z), a5 = bf16_hi(qs.z);
    float a6 = bf16_lo(qs.w), a7 = bf16_hi(qs.w);

    const int* rp = rec + j0;
    int tt = 0;
    for (; tt + 8 <= deg; tt += 8) {
        int s[8]; uint4 q[8];
#pragma unroll
        for (int u = 0; u < 8; u++) s[u] = rp[tt + u];
#pragma unroll
        for (int u = 0; u < 8; u++) q[u] = h4[(size_t)s[u] * 8 + fl];
#pragma unroll
        for (int u = 0; u < 8; u++) {
            a0 += bf16_lo(q[u].x); a1 += bf16_hi(q[u].x);
            a2 += bf16_lo(q[u].y); a3 += bf16_hi(q[u].y);
            a4 += bf16_lo(q[u].z); a5 += bf16_hi(q[u].z);
            a6 += bf16_lo(q[u].w); a7 += bf16_hi(q[u].w);
        }
    }
    for (; tt + 2 <= deg; tt += 2) {
        int s0i = rp[tt], s1i = rp[tt + 1];
        uint4 q0 = h4[(size_t)s0i * 8 + fl];
        uint4 q1 = h4[(size_t)s1i * 8 + fl];
        a0 += bf16_lo(q0.x) + bf16_lo(q1.x);
        a1 += bf16_hi(q0.x) + bf16_hi(q1.x);
        a2 += bf16_lo(q0.y) + bf16_lo(q1.y);
        a3 += bf16_hi(q0.y) + bf16_hi(q1.y);
        a4 += bf16_lo(q0.z) + bf16_lo(q1.z);
        a5 += bf16_hi(q0.z) + bf16_hi(q1.z);
        a6 += bf16_lo(q0.w) + bf16_lo(q1.w);
        a7 += bf16_hi(q0.w) + bf16_hi(q1.w);
    }
    if (tt < deg) {
        int s = rp[tt];
        uint4 q0 = h4[(size_t)s * 8 + fl];
        a0 += bf16_lo(q0.x); a1 += bf16_hi(q0.x);
        a2 += bf16_lo(q0.y); a3 += bf16_hi(q0.y);
        a4 += bf16_lo(q0.z); a5 += bf16_hi(q0.z);
        a6 += bf16_lo(q0.w); a7 += bf16_hi(q0.w);
    }

    float4 bb0 = *(const float4*)&bias[8 * fl];
    float4 bb1 = *(const float4*)&bias[8 * fl + 4];
    floatx4 o0, o1;
    o0[0] = di * a0 + bb0.x; o0[1] = di * a1 + bb0.y;
    o0[2] = di * a2 + bb0.z; o0[3] = di * a3 + bb0.w;
    o1[0] = di * a4 + bb1.x; o1[1] = di * a5 + bb1.y;
    o1[2] = di * a6 + bb1.z; o1[3] = di * a7 + bb1.w;
    __builtin_nontemporal_store(o0, (floatx4*)&out[(size_t)w * 64 + 8 * fl]);
    __builtin_nontemporal_store(o1, (floatx4*)&out[(size_t)w * 64 + 8 * fl + 4]);
}

extern "C" void kernel_launch(void* const* d_in, const int* in_sizes, int n_in,
                              void* d_out, int out_size, void* d_ws, size_t ws_size,
                              hipStream_t stream) {
    const float* x = (const float*)d_in[0];
    const int* edge = (const int*)d_in[1];
    const float* W1 = (const float*)d_in[2];
    const float* b1 = (const float*)d_in[3];
    const float* W2 = (const float*)d_in[4];
    const float* b2 = (const float*)d_in[5];

    const int N = in_sizes[0] / 128;
    const int E = in_sizes[1] / 2;
    const int* src = edge;
    const int* dst = edge + E;
    const int NB = (N + (1 << BSH) - 1) >> BSH;   // coarse buckets (<= 512)

    // workspace carve-up (all chunks 16B-aligned for these sizes)
    char* p = (char*)d_ws;
    int* bfill = (int*)p;     p += NBMAX * 4;           // bucket fill counts
    float* dinv = (float*)p;  p += (size_t)N * 4;
    int4* meta = (int4*)p;    p += (size_t)N * 16;      // (start, deg, dinv, dinv^2)
    int* rec = (int*)p;       p += (size_t)E * 4;       // src per edge (CSR by dst)
    uint* staged = (uint*)p;  p += (size_t)NBMAX * BCAP * 4;  // fixed bucket regions
    uint* hq = (uint*)p;      p += (size_t)N * 64 * 4;  // RAW x@W1, bf16 pairs
    uint* h2q = (uint*)p;     p += (size_t)N * 32 * 4;  // dinv[r]*h2, bf16 (64 feats)

    float* out = (float*)d_out;
    const int eblocks = (E + 2047) / 2048;
    const int gblocks = (N + 63) / 64;

    (void)hipMemsetAsync(bfill, 0, NBMAX * 4, stream);
    // merged: edge partition + layer-1 GEMM (independent block families)
    part_gemm1<<<eblocks + gblocks, 256, 0, stream>>>(
        src, dst, bfill, staged, E, NB, eblocks, x, W1, hq, N);
    fine_csr_kernel<<<NB, 256, 0, stream>>>(staged, bfill, meta, dinv, rec, N);
    // fused: g = relu(sum of weighted raw rows + b1); h2q = dinv .* (g @ W2)
    agg128_mm64<<<(N + 31) / 32, 512, 0, stream>>>(hq, rec, meta, dinv, b1, W2, h2q, N);
    // layer 2 aggregation: out = di*(sum of pre-scaled h2 rows) + b2
    aggregate64q<<<(N * 8 + 255) / 256, 256, 0, stream>>>(h2q, rec, meta, b2, out, N);
}